// Round 14
// baseline (1028.322 us; speedup 1.0000x reference)
//
#include <hip/hip_runtime.h>
#include <hip/hip_bf16.h>

// All tensors fp32. Output = [y (2048) | hT (2*1024*32)] fp32.
#define NPER 128

typedef __attribute__((ext_vector_type(8))) short s8v;   // 8 bf16 (4 VGPRs)
typedef __attribute__((ext_vector_type(4))) float f4v;   // MFMA accum

__device__ __forceinline__ unsigned short f2bf(float x) {   // RNE bf16
    unsigned u = __float_as_uint(x);
    unsigned r = u + 0x7FFFu + ((u >> 16) & 1u);
    return (unsigned short)(r >> 16);
}
__device__ __forceinline__ float bf2f(unsigned short b) {
    return __uint_as_float(((unsigned)b) << 16);
}

// branchless stable top-4 insert, strict < (earlier candidate wins ties)
__device__ __forceinline__ void ins4(float d, int id, float* bd, int* bi) {
    const bool c0 = d < bd[0], c1 = d < bd[1], c2 = d < bd[2], c3 = d < bd[3];
    bd[3] = c2 ? bd[2] : (c3 ? d : bd[3]);  bi[3] = c2 ? bi[2] : (c3 ? id : bi[3]);
    bd[2] = c1 ? bd[1] : (c2 ? d : bd[2]);  bi[2] = c1 ? bi[1] : (c2 ? id : bi[2]);
    bd[1] = c0 ? bd[0] : (c1 ? d : bd[1]);  bi[1] = c0 ? bi[0] : (c1 ? id : bi[1]);
    bd[0] = c0 ? d : bd[0];                 bi[0] = c0 ? id : bi[0];
}

// ---------------------------------------------------------------------------
// k_prep (R7-verified): nn2WT[64][94]; WfT[96][256]; WB = W2 as MFMA
// B-fragments, bf16 hi/lo. Frag order: j = ((ks*8+nt)*64 + lane)*8 + e holds
// W2[ks*32 + (lane>>4)*8 + e][nt*16 + (lane&15)].
// ---------------------------------------------------------------------------
__global__ void k_prep(const float* __restrict__ W2,
                       const float* __restrict__ nn2W,
                       const float* __restrict__ nn1W,
                       float* __restrict__ nn2WT, float* __restrict__ WfT,
                       unsigned short* __restrict__ WBhi,
                       unsigned short* __restrict__ WBlo)
{
    int i = blockIdx.x * 256 + threadIdx.x;
    if (i < 6016) {                       // nn2WT
        int ch = i / 94, c = i - ch * 94;
        nn2WT[i] = nn2W[c * 64 + ch];
    } else if (i < 30592) {               // WfT (96 rows x 256)
        int k = i - 6016, jj = k >> 8, r = k & 255;
        float v = 0.0f;
        if (jj < 94) {
            if (r < 128) v = nn1W[r * 94 + jj];
            else {
                int c = r - 128;
                v = 0.25f * nn1W[(128 + c) * 94 + jj] + nn1W[(256 + c) * 94 + jj];
            }
        }
        WfT[k] = v;
    } else if (i < 38784) {               // WB fragments (8192 elements)
        int j = i - 30592;
        int e = j & 7, l = (j >> 3) & 63, nt = (j >> 9) & 7, ks = j >> 12;
        int kk = ks * 32 + ((l >> 4) << 3) + e;
        int n  = nt * 16 + (l & 15);
        float v = W2[kk * 128 + n];
        unsigned short hb = f2bf(v);
        WBhi[j] = hb;
        WBlo[j] = f2bf(v - bf2f(hb));
    }
}

// ---------------------------------------------------------------------------
// k_edge: block = (graph, half of 64 nodes), 256 threads = 4 waves.
// R14 = R12 (776us session best) with ONE fix: the chunk loop `for (c)` is
// FULLY UNROLLED. R12 had `#pragma unroll 1` there, and mxq/smq[c][..] with
// runtime c => compiler placed them in SCRATCH (rule #20: runtime-indexed
// arrays -> localMem). Counter signature: WRITE 125MB >> FETCH 13MB (scratch
// stores stream to HBM; readbacks cache-hit). Unrolling makes every mxq/smq
// index compile-time => registers. Arithmetic bit-identical to R12.
// R13's two-half MLP1 is REVERTED (it regressed: occupancy flat at 22.8%,
// WRITE grew to 140MB, k_edge 683->825 -- occupancy quantum is coarser than
// the <=170 model; not worth more register shaving).
// WRITE_SIZE >= 50MB next run = scratch source elsewhere -> disasm evidence.
// ---------------------------------------------------------------------------
__global__ __launch_bounds__(256, 2) void k_edge(
    const float* __restrict__ x,      // [N,5]
    const float* __restrict__ W1,     // [10,64]
    const float* __restrict__ b1,     // [64]
    const float* __restrict__ b2,     // [128]
    const unsigned short* __restrict__ WBhi,  // [2][8][64][8] bf16 hi
    const unsigned short* __restrict__ WBlo,  // bf16 lo
    const float* __restrict__ WfT,    // [96,256]
    const float* __restrict__ nn1b,   // [94]
    const float* __restrict__ nn2WT,  // [64,94]
    const float* __restrict__ nn2b,   // [64]
    float* __restrict__ pmax,         // [4096,64]
    float* __restrict__ pmin,
    float* __restrict__ psum)
{
    __shared__ float pool[10240];     // 40960 B
    float* XS  = pool;                        // [640]   phases 1-3 (MLP1 uses)
    int*   NBR = (int*)(pool + 640);          // [256]   phases 1-3
    float* KD  = pool + 896;                  // [1024]  phase 1 only
    int*   KI  = (int*)(pool + 1920);         // [1024]  phase 1 only
    unsigned short* PH16 = (unsigned short*)(pool + 1024);  // A-hi [128][72]
    unsigned short* PL16 = (unsigned short*)(pool + 5632);  // A-lo [128][72]
    float* AGM = pool + 1024;                 // [4096]  (64x64 swz) per half
    float* AGS = pool + 5120;                 // [4096]
    float* NNH = pool;                        // [6016]  phase 4 (94x64)
    float* HT  = pool + 6016;                 // [4224]  phase 4b

    const int t = threadIdx.x;
    const int lane = t & 63;
    const int w = __builtin_amdgcn_readfirstlane(t >> 6);
    const int graph = blockIdx.x >> 1;
    const int node0 = (blockIdx.x & 1) * 64;

    for (int i = t; i < NPER * 5; i += 256) XS[i] = x[(size_t)graph * (NPER * 5) + i];
    __syncthreads();

    // ---- KNN: 4 threads per node (q = t>>6), branchless insert, LDS merge
    {
        const int nl2 = t & 63;
        const int q  = t >> 6;
        const int ng2 = node0 + nl2;
        const float px = XS[ng2 * 5 + 0], py = XS[ng2 * 5 + 1], pz = XS[ng2 * 5 + 2];
        float bd[4] = {3e38f, 3e38f, 3e38f, 3e38f};
        int   bi[4] = {0, 0, 0, 0};
        const int m0 = q * 32;
        for (int m = m0; m < m0 + 32; ++m) {
            float dx = XS[m * 5 + 0] - px, dy = XS[m * 5 + 1] - py, dz = XS[m * 5 + 2] - pz;
            float d2 = __fadd_rn(__fadd_rn(__fmul_rn(dx, dx), __fmul_rn(dy, dy)),
                                 __fmul_rn(dz, dz));
            d2 = (m == ng2) ? 3.0e38f : d2;   // self never inserted (strict <)
            ins4(d2, m, bd, bi);
        }
        #pragma unroll
        for (int s = 0; s < 4; ++s) { KD[(q * 4 + s) * 64 + nl2] = bd[s]; KI[(q * 4 + s) * 64 + nl2] = bi[s]; }
    }
    __syncthreads();
    if (t < 64) {                           // merge quarters in global index order
        float bd[4] = {3e38f, 3e38f, 3e38f, 3e38f};
        int   bi[4] = {0, 0, 0, 0};
        #pragma unroll
        for (int q = 0; q < 4; ++q)
            #pragma unroll
            for (int s = 0; s < 4; ++s)
                ins4(KD[(q * 4 + s) * 64 + t], KI[(q * 4 + s) * 64 + t], bd, bi);
        #pragma unroll
        for (int s = 0; s < 4; ++s) NBR[t * 4 + s] = bi[s];
    }
    __syncthreads();

    // ---- nn1 accumulators (wave owns 24 jj channels, node = lane)
    float acc[24];
    const int jj0 = __builtin_amdgcn_readfirstlane(w * 24);
    #pragma unroll
    for (int i = 0; i < 24; ++i) acc[i] = (jj0 + i < 94) ? nn1b[jj0 + i] : 0.0f;

    // ---- HALF-MAJOR GEMM1 + nn1: for each 64-channel half of MLP2's output
    #pragma unroll 1
    for (int hf = 0; hf < 2; ++hf) {
        float mxq[2][2][4], smq[2][2][4];     // this half's agg [chunk][m][q]
        #pragma unroll
        for (int c = 0; c < 2; ++c) {         // FULLY UNROLLED (rule #20 fix)
            if ((t >> 7) == c) {              // wave-uniform stage (waves 2c,2c+1)
                // MLP1 (recomputed per half -- bitwise-identical h1v)
                const int nl = t >> 2;
                const int kk = t & 3;
                const int n_g = node0 + nl;
                const int j   = NBR[nl * 4 + kk];
                float f[10];
                #pragma unroll
                for (int d = 0; d < 5; ++d) { f[d] = XS[n_g * 5 + d]; f[5 + d] = XS[j * 5 + d] - f[d]; }
                float h1v[64];
                #pragma unroll
                for (int cc = 0; cc < 64; ++cc) h1v[cc] = b1[cc];
                #pragma unroll
                for (int d = 0; d < 10; ++d) {
                    float fd = f[d];
                    #pragma unroll
                    for (int cc = 0; cc < 64; ++cc) h1v[cc] = fmaf(fd, W1[d * 64 + cc], h1v[cc]);
                }
                #pragma unroll
                for (int cc = 0; cc < 64; ++cc) h1v[cc] = fmaxf(h1v[cc], 0.0f);

                // pack to bf16 hi/lo planes, row = t&127
                const int rl = t & 127;
                unsigned int* dh = (unsigned int*)PH16 + rl * 36;
                unsigned int* dl = (unsigned int*)PL16 + rl * 36;
                #pragma unroll
                for (int i = 0; i < 8; ++i) {
                    unsigned int hw[4], lw[4];
                    #pragma unroll
                    for (int p = 0; p < 4; ++p) {
                        float va = h1v[i * 8 + p * 2], vb = h1v[i * 8 + p * 2 + 1];
                        unsigned short ha = f2bf(va), hb = f2bf(vb);
                        unsigned short la = f2bf(va - bf2f(ha)), lb = f2bf(vb - bf2f(hb));
                        hw[p] = (unsigned)ha | ((unsigned)hb << 16);
                        lw[p] = (unsigned)la | ((unsigned)lb << 16);
                    }
                    *(uint4*)(dh + 4 * i) = make_uint4(hw[0], hw[1], hw[2], hw[3]);
                    *(uint4*)(dl + 4 * i) = make_uint4(lw[0], lw[1], lw[2], lw[3]);
                }
            }
            __syncthreads();   // planes staged for chunk c

            f4v C[2][4];
            #pragma unroll
            for (int q = 0; q < 4; ++q) {
                float bv = b2[hf * 64 + q * 16 + (lane & 15)];
                #pragma unroll
                for (int m = 0; m < 2; ++m) {
                    C[m][q][0] = bv; C[m][q][1] = bv; C[m][q][2] = bv; C[m][q][3] = bv;
                }
            }
            #pragma unroll
            for (int ks = 0; ks < 2; ++ks) {
                s8v ah[2], al[2];
                #pragma unroll
                for (int m = 0; m < 2; ++m) {
                    const int row = (w << 5) + (m << 4) + (lane & 15);
                    const int ui  = row * 72 + (ks << 5) + ((lane >> 4) << 3);
                    ah[m] = *(const s8v*)(PH16 + ui);
                    al[m] = *(const s8v*)(PL16 + ui);
                }
                #pragma unroll
                for (int q = 0; q < 4; ++q) {
                    const int nt = hf * 4 + q;
                    const int bidx = ((((ks << 3) | nt) << 6) | lane) << 3;
                    s8v bh = *(const s8v*)(WBhi + bidx);
                    s8v bl = *(const s8v*)(WBlo + bidx);
                    #pragma unroll
                    for (int m = 0; m < 2; ++m) {
                        f4v cc = C[m][q];
                        cc = __builtin_amdgcn_mfma_f32_16x16x32_bf16(al[m], bh, cc, 0, 0, 0);
                        cc = __builtin_amdgcn_mfma_f32_16x16x32_bf16(ah[m], bl, cc, 0, 0, 0);
                        cc = __builtin_amdgcn_mfma_f32_16x16x32_bf16(ah[m], bh, cc, 0, 0, 0);
                        C[m][q] = cc;
                    }
                }
            }
            // relu + reduce over the lane's 4 rows (= one node's 4 edges)
            #pragma unroll
            for (int m = 0; m < 2; ++m)
                #pragma unroll
                for (int q = 0; q < 4; ++q) {
                    float a0 = fmaxf(C[m][q][0], 0.0f), a1 = fmaxf(C[m][q][1], 0.0f);
                    float a2 = fmaxf(C[m][q][2], 0.0f), a3 = fmaxf(C[m][q][3], 0.0f);
                    mxq[c][m][q] = fmaxf(fmaxf(a0, a1), fmaxf(a2, a3));
                    smq[c][m][q] = (a0 + a1) + (a2 + a3);
                }
            __syncthreads();   // planes consumed; next stage / AGM alias safe
        }

        // scatter this half's agg into AGM/AGS (R1-verified swizzled layout)
        #pragma unroll
        for (int c2 = 0; c2 < 2; ++c2)
            #pragma unroll
            for (int m = 0; m < 2; ++m)
                #pragma unroll
                for (int q = 0; q < 4; ++q) {
                    const int node = (c2 << 5) + (w << 3) + (m << 2) + (lane >> 4);
                    const int chl  = (q << 4) + (lane & 15);
                    const int ad   = (node << 6) + ((((chl >> 2) ^ node) & 15) << 2) + (chl & 3);
                    AGM[ad] = mxq[c2][m][q];
                    AGS[ad] = smq[c2][m][q];
                }
        __syncthreads();

        // nn1 partial for half hf: lane = node; agg rows via b128, chunks of 8
        for (int cb = 0; cb < 64; cb += 8) {
            float am[8], as_[8];
            #pragma unroll
            for (int i = 0; i < 2; ++i) {
                const int sw = ((((cb >> 2) + i) ^ lane) & 15) << 2;
                *(float4*)&am[i * 4]  = *(const float4*)&AGM[(lane << 6) + sw];
                *(float4*)&as_[i * 4] = *(const float4*)&AGS[(lane << 6) + sw];
            }
            #pragma unroll
            for (int i2 = 0; i2 < 24; ++i2) {
                const float* wa = WfT + (size_t)(jj0 + i2) * 256 + hf * 64 + cb;
                const float* wb = wa + 128;
                float a = acc[i2];
                #pragma unroll
                for (int i = 0; i < 8; ++i) a = fmaf(am[i], wa[i], fmaf(as_[i], wb[i], a));
                acc[i2] = a;
            }
        }
        __syncthreads();   // AGM/AGS dead; next half may restage planes
    }

    // ---- nnh = relu(nn1), channel-major [jj][node] (conflict-free stride 64)
    #pragma unroll
    for (int i2 = 0; i2 < 24; ++i2)
        if (jj0 + i2 < 94) NNH[(jj0 + i2) * 64 + lane] = fmaxf(acc[i2], 0.0f);
    __syncthreads();

    // ---- nn2: lane = node, wave owns 16 output channels (weights s_load).
    {
        const int ch0 = __builtin_amdgcn_readfirstlane(w * 16);
        float acc2[16];
        #pragma unroll
        for (int i = 0; i < 16; ++i) acc2[i] = nn2b[ch0 + i];
        #pragma unroll 1
        for (int cb = 0; cb < 64; cb += 32) {
            float hv[32];
            #pragma unroll
            for (int i = 0; i < 32; ++i) hv[i] = NNH[(cb + i) * 64 + lane];
            #pragma unroll
            for (int i = 0; i < 16; ++i) {
                const float* wp = nn2WT + (size_t)(ch0 + i) * 94 + cb;
                float a = acc2[i];
                #pragma unroll
                for (int c = 0; c < 32; ++c) a = fmaf(hv[c], wp[c], a);
                acc2[i] = a;
            }
        }
        {   // tail c = 64..93 (constant trip 30)
            float hv[30];
            #pragma unroll
            for (int i = 0; i < 30; ++i) hv[i] = NNH[(64 + i) * 64 + lane];
            #pragma unroll
            for (int i = 0; i < 16; ++i) {
                const float* wp = nn2WT + (size_t)(ch0 + i) * 94 + 64;
                float a = acc2[i];
                #pragma unroll
                for (int c = 0; c < 30; ++c) a = fmaf(hv[c], wp[c], a);
                acc2[i] = a;
            }
        }
        __syncthreads();   // NNH fully consumed; HT may alias
        #pragma unroll
        for (int i = 0; i < 8; ++i)
            *(float2*)&HT[lane * 66 + ch0 + i * 2] =
                make_float2(acc2[i * 2], acc2[i * 2 + 1]);
    }
    __syncthreads();

    // ---- partial pooling over this block's 64 nodes
    if (t < 64) {
        float mx = -3e38f, mn = 3e38f, sm = 0.0f;
        for (int n = 0; n < 64; ++n) {
            float v = HT[n * 66 + t];
            mx = fmaxf(mx, v); mn = fminf(mn, v); sm += v;
        }
        pmax[(size_t)blockIdx.x * 64 + t] = mx;
        pmin[(size_t)blockIdx.x * 64 + t] = mn;
        psum[(size_t)blockIdx.x * 64 + t] = sm;
    }
}

// ---------------------------------------------------------------------------
__global__ void k_pool(const float* __restrict__ pmax, const float* __restrict__ pmin,
                       const float* __restrict__ psum, float* __restrict__ g_out)
{
    const int t = threadIdx.x;
    const int g = blockIdx.x * 4 + (t >> 6);
    const int ch = t & 63;
    const size_t a = (size_t)(2 * g) * 64 + ch, b = a + 64;
    float mx = fmaxf(pmax[a], pmax[b]);
    float mn = fminf(pmin[a], pmin[b]);
    float sm = psum[a] + psum[b];
    float* gp = g_out + (size_t)g * 256;
    gp[ch]        = fmaxf(mx, 0.0f);
    gp[64 + ch]   = fmaxf(mn, 0.0f);
    gp[128 + ch]  = fmaxf(sm, 0.0f);
    gp[192 + ch]  = fmaxf(sm * (1.0f / 128.0f), 0.0f);
}

// ---------------------------------------------------------------------------
__global__ __launch_bounds__(128) void k_gru(
    const float* __restrict__ g, const float* __restrict__ h1_in,
    const float* __restrict__ wih0, const float* __restrict__ whh0,
    const float* __restrict__ bih0, const float* __restrict__ bhh0,
    const float* __restrict__ wih1, const float* __restrict__ whh1,
    const float* __restrict__ bih1, const float* __restrict__ bhh1,
    float* __restrict__ out1, float* __restrict__ hT)
{
    __shared__ float xt[4][256];
    __shared__ float h0[4][32];
    __shared__ float h1l[4][32];
    const int tid = threadIdx.x;
    const int e = tid >> 5;
    const int j = tid & 31;
    const int b = blockIdx.x * 4 + e;

    h0[e][j]  = h1_in[b * 32 + j];
    h1l[e][j] = h1_in[32768 + b * 32 + j];
    __syncthreads();

    for (int t = 0; t < 2; ++t) {
        for (int c = j; c < 256; c += 32)
            xt[e][c] = g[(size_t)(t * 1024 + 4 * c + (b >> 8)) * 256 + (b & 255)];
        __syncthreads();

        float gi0 = bih0[j], gi1 = bih0[32 + j], gi2 = bih0[64 + j];
        for (int c = 0; c < 256; ++c) {
            float xv = xt[e][c];
            gi0 += xv * wih0[j * 256 + c];
            gi1 += xv * wih0[(32 + j) * 256 + c];
            gi2 += xv * wih0[(64 + j) * 256 + c];
        }
        float gh0 = bhh0[j], gh1 = bhh0[32 + j], gh2 = bhh0[64 + j];
        #pragma unroll
        for (int c = 0; c < 32; ++c) {
            float hv = h0[e][c];
            gh0 += hv * whh0[j * 32 + c];
            gh1 += hv * whh0[(32 + j) * 32 + c];
            gh2 += hv * whh0[(64 + j) * 32 + c];
        }
        float r = 1.0f / (1.0f + expf(-(gi0 + gh0)));
        float z = 1.0f / (1.0f + expf(-(gi1 + gh1)));
        float nn = tanhf(gi2 + r * gh2);
        float hn0 = (1.0f - z) * nn + z * h0[e][j];
        __syncthreads();
        h0[e][j] = hn0;
        __syncthreads();

        float ai0 = bih1[j], ai1 = bih1[32 + j], ai2 = bih1[64 + j];
        #pragma unroll
        for (int c = 0; c < 32; ++c) {
            float xv = h0[e][c];
            ai0 += xv * wih1[j * 32 + c];
            ai1 += xv * wih1[(32 + j) * 32 + c];
            ai2 += xv * wih1[(64 + j) * 32 + c];
        }
        float ah0 = bhh1[j], ah1 = bhh1[32 + j], ah2 = bhh1[64 + j];
        #pragma unroll
        for (int c = 0; c < 32; ++c) {
            float hv = h1l[e][c];
            ah0 += hv * whh1[j * 32 + c];
            ah1 += hv * whh1[(32 + j) * 32 + c];
            ah2 += hv * whh1[(64 + j) * 32 + c];
        }
        float r1 = 1.0f / (1.0f + expf(-(ai0 + ah0)));
        float z1 = 1.0f / (1.0f + expf(-(ai1 + ah1)));
        float n1 = tanhf(ai2 + r1 * ah2);
        float hn1 = (1.0f - z1) * n1 + z1 * h1l[e][j];
        __syncthreads();
        h1l[e][j] = hn1;
        out1[(size_t)(t * 1024 + b) * 32 + j] = hn1;
        __syncthreads();
    }
    hT[b * 32 + j]         = h0[e][j];
    hT[32768 + b * 32 + j] = h1l[e][j];
}

__global__ void k_final(const float* __restrict__ out1,
                        const float* __restrict__ nn4W, const float* __restrict__ nn4b,
                        float* __restrict__ y)
{
    const int r = blockIdx.x * 256 + threadIdx.x;
    if (r >= 2048) return;
    const int t = r >> 10, rp = r & 1023;
    const int f = rp >> 5, bb0 = (rp & 31) << 5;
    float acc = nn4b[0];
    #pragma unroll
    for (int c = 0; c < 32; ++c)
        acc += fmaxf(out1[(size_t)(t * 1024 + bb0 + c) * 32 + f], 0.0f) * nn4W[c];
    y[r] = fmaxf(acc, 0.0f);
}

extern "C" void kernel_launch(void* const* d_in, const int* in_sizes, int n_in,
                              void* d_out, int out_size, void* d_ws, size_t ws_size,
                              hipStream_t stream) {
    const float* x    = (const float*)d_in[0];
    const float* h1i  = (const float*)d_in[2];
    const float* W1   = (const float*)d_in[3];
    const float* b1   = (const float*)d_in[4];
    const float* W2   = (const float*)d_in[5];
    const float* b2   = (const float*)d_in[6];
    const float* nn1W = (const float*)d_in[7];
    const float* nn1b = (const float*)d_in[8];
    const float* nn2W = (const float*)d_in[9];
    const float* nn2b = (const float*)d_in[10];
    const float* nn4W = (const float*)d_in[11];
    const float* nn4b = (const float*)d_in[12];
    const float* wih0 = (const float*)d_in[13];
    const float* whh0 = (const float*)d_in[14];
    const float* bih0 = (const float*)d_in[15];
    const float* bhh0 = (const float*)d_in[16];
    const float* wih1 = (const float*)d_in[17];
    const float* whh1 = (const float*)d_in[18];
    const float* bih1 = (const float*)d_in[19];
    const float* bhh1 = (const float*)d_in[20];

    float* ws = (float*)d_ws;
    float* g_buf  = ws;                   // 524288
    float* out1   = g_buf + 524288;       // 65536
    float* nn2WT  = out1 + 65536;         // 6016
    float* WfT    = nn2WT + 6016;         // 24576 (96x256)
    float* pmax   = WfT + 24576;          // 262144
    float* pmin   = pmax + 262144;        // 262144
    float* psum   = pmin + 262144;        // 262144
    unsigned short* WBhi = (unsigned short*)(psum + 262144);  // 8192 u16
    unsigned short* WBlo = WBhi + 8192;                       // 8192 u16

    float* y  = (float*)d_out;            // [2048]
    float* hT = y + 2048;                 // [2,1024,32]

    hipLaunchKernelGGL(k_prep, dim3(152), dim3(256), 0, stream,
                       W2, nn2W, nn1W, nn2WT, WfT, WBhi, WBlo);
    hipLaunchKernelGGL(k_edge, dim3(4096), dim3(256), 0, stream,
                       x, W1, b1, b2, WBhi, WBlo, WfT, nn1b, nn2WT, nn2b,
                       pmax, pmin, psum);
    hipLaunchKernelGGL(k_pool, dim3(512), dim3(256), 0, stream,
                       pmax, pmin, psum, g_buf);
    hipLaunchKernelGGL(k_gru, dim3(256), dim3(128), 0, stream,
                       g_buf, h1i, wih0, whh0, bih0, bhh0,
                       wih1, whh1, bih1, bhh1, out1, hT);
    hipLaunchKernelGGL(k_final, dim3(8), dim3(256), 0, stream,
                       out1, nn4W, nn4b, y);
}

// Round 15
// 774.012 us; speedup vs baseline: 1.3286x; 1.3286x over previous
//
#include <hip/hip_runtime.h>
#include <hip/hip_bf16.h>

// All tensors fp32. Output = [y (2048) | hT (2*1024*32)] fp32.
#define NPER 128

typedef __attribute__((ext_vector_type(8))) short s8v;   // 8 bf16 (4 VGPRs)
typedef __attribute__((ext_vector_type(4))) float f4v;   // MFMA accum

__device__ __forceinline__ unsigned short f2bf(float x) {   // RNE bf16
    unsigned u = __float_as_uint(x);
    unsigned r = u + 0x7FFFu + ((u >> 16) & 1u);
    return (unsigned short)(r >> 16);
}
__device__ __forceinline__ float bf2f(unsigned short b) {
    return __uint_as_float(((unsigned)b) << 16);
}

// branchless stable top-4 insert, strict < (earlier candidate wins ties)
__device__ __forceinline__ void ins4(float d, int id, float* bd, int* bi) {
    const bool c0 = d < bd[0], c1 = d < bd[1], c2 = d < bd[2], c3 = d < bd[3];
    bd[3] = c2 ? bd[2] : (c3 ? d : bd[3]);  bi[3] = c2 ? bi[2] : (c3 ? id : bi[3]);
    bd[2] = c1 ? bd[1] : (c2 ? d : bd[2]);  bi[2] = c1 ? bi[1] : (c2 ? id : bi[2]);
    bd[1] = c0 ? bd[0] : (c1 ? d : bd[1]);  bi[1] = c0 ? bi[0] : (c1 ? id : bi[1]);
    bd[0] = c0 ? d : bd[0];                 bi[0] = c0 ? id : bi[0];
}

// ---------------------------------------------------------------------------
// k_prep (R7-verified): nn2WT[64][94]; WfT[96][256]; WB = W2 as MFMA
// B-fragments, bf16 hi/lo. Frag order: j = ((ks*8+nt)*64 + lane)*8 + e holds
// W2[ks*32 + (lane>>4)*8 + e][nt*16 + (lane&15)].
// ---------------------------------------------------------------------------
__global__ void k_prep(const float* __restrict__ W2,
                       const float* __restrict__ nn2W,
                       const float* __restrict__ nn1W,
                       float* __restrict__ nn2WT, float* __restrict__ WfT,
                       unsigned short* __restrict__ WBhi,
                       unsigned short* __restrict__ WBlo)
{
    int i = blockIdx.x * 256 + threadIdx.x;
    if (i < 6016) {                       // nn2WT
        int ch = i / 94, c = i - ch * 94;
        nn2WT[i] = nn2W[c * 64 + ch];
    } else if (i < 30592) {               // WfT (96 rows x 256)
        int k = i - 6016, jj = k >> 8, r = k & 255;
        float v = 0.0f;
        if (jj < 94) {
            if (r < 128) v = nn1W[r * 94 + jj];
            else {
                int c = r - 128;
                v = 0.25f * nn1W[(128 + c) * 94 + jj] + nn1W[(256 + c) * 94 + jj];
            }
        }
        WfT[k] = v;
    } else if (i < 38784) {               // WB fragments (8192 elements)
        int j = i - 30592;
        int e = j & 7, l = (j >> 3) & 63, nt = (j >> 9) & 7, ks = j >> 12;
        int kk = ks * 32 + ((l >> 4) << 3) + e;
        int n  = nt * 16 + (l & 15);
        float v = W2[kk * 128 + n];
        unsigned short hb = f2bf(v);
        WBhi[j] = hb;
        WBlo[j] = f2bf(v - bf2f(hb));
    }
}

// ---------------------------------------------------------------------------
// k_edge: block = (graph, half of 64 nodes), 256 threads = 4 waves.
// R15 = R12 byte-for-byte (session best: 776us total / 683us k_edge,
// absmax 0.00390625). Locked in after the full lever sweep:
//  - R12 structure: HALF-MAJOR GEMM (MFMA GEMM1 bf16 hi/lo, exact fp32 agg,
//    VALU nn1), MLP1 recomputed per half inside the owning chunk's stage
//    branch, launch_bounds(256,2).
//  - The `#pragma unroll 1` chunk loop puts mxq/smq[c] in SCRATCH (WRITE
//    ~125MB) -- measured BENIGN: overlaps compute. R14 proved removing it
//    (full unroll -> registers) costs MORE: compiler rematerializes, VALU
//    -issue 242->385us, k_edge 683->940. KEEP the scratch.
//  - R13 (two-half MLP1): occupancy flat, +regression. R8/R9 (nn1 on MFMA):
//    correctness failures (structural, unfound after 3 audits). R11
//    (quarter-major): restage overhead > register win. All rejected.
// ---------------------------------------------------------------------------
__global__ __launch_bounds__(256, 2) void k_edge(
    const float* __restrict__ x,      // [N,5]
    const float* __restrict__ W1,     // [10,64]
    const float* __restrict__ b1,     // [64]
    const float* __restrict__ b2,     // [128]
    const unsigned short* __restrict__ WBhi,  // [2][8][64][8] bf16 hi
    const unsigned short* __restrict__ WBlo,  // bf16 lo
    const float* __restrict__ WfT,    // [96,256]
    const float* __restrict__ nn1b,   // [94]
    const float* __restrict__ nn2WT,  // [64,94]
    const float* __restrict__ nn2b,   // [64]
    float* __restrict__ pmax,         // [4096,64]
    float* __restrict__ pmin,
    float* __restrict__ psum)
{
    __shared__ float pool[10240];     // 40960 B
    float* XS  = pool;                        // [640]   phases 1-3 (MLP1 uses)
    int*   NBR = (int*)(pool + 640);          // [256]   phases 1-3
    float* KD  = pool + 896;                  // [1024]  phase 1 only
    int*   KI  = (int*)(pool + 1920);         // [1024]  phase 1 only
    unsigned short* PH16 = (unsigned short*)(pool + 1024);  // A-hi [128][72]
    unsigned short* PL16 = (unsigned short*)(pool + 5632);  // A-lo [128][72]
    float* AGM = pool + 1024;                 // [4096]  (64x64 swz) per half
    float* AGS = pool + 5120;                 // [4096]
    float* NNH = pool;                        // [6016]  phase 4 (94x64)
    float* HT  = pool + 6016;                 // [4224]  phase 4b

    const int t = threadIdx.x;
    const int lane = t & 63;
    const int w = __builtin_amdgcn_readfirstlane(t >> 6);
    const int graph = blockIdx.x >> 1;
    const int node0 = (blockIdx.x & 1) * 64;

    for (int i = t; i < NPER * 5; i += 256) XS[i] = x[(size_t)graph * (NPER * 5) + i];
    __syncthreads();

    // ---- KNN: 4 threads per node (q = t>>6), branchless insert, LDS merge
    {
        const int nl2 = t & 63;
        const int q  = t >> 6;
        const int ng2 = node0 + nl2;
        const float px = XS[ng2 * 5 + 0], py = XS[ng2 * 5 + 1], pz = XS[ng2 * 5 + 2];
        float bd[4] = {3e38f, 3e38f, 3e38f, 3e38f};
        int   bi[4] = {0, 0, 0, 0};
        const int m0 = q * 32;
        for (int m = m0; m < m0 + 32; ++m) {
            float dx = XS[m * 5 + 0] - px, dy = XS[m * 5 + 1] - py, dz = XS[m * 5 + 2] - pz;
            float d2 = __fadd_rn(__fadd_rn(__fmul_rn(dx, dx), __fmul_rn(dy, dy)),
                                 __fmul_rn(dz, dz));
            d2 = (m == ng2) ? 3.0e38f : d2;   // self never inserted (strict <)
            ins4(d2, m, bd, bi);
        }
        #pragma unroll
        for (int s = 0; s < 4; ++s) { KD[(q * 4 + s) * 64 + nl2] = bd[s]; KI[(q * 4 + s) * 64 + nl2] = bi[s]; }
    }
    __syncthreads();
    if (t < 64) {                           // merge quarters in global index order
        float bd[4] = {3e38f, 3e38f, 3e38f, 3e38f};
        int   bi[4] = {0, 0, 0, 0};
        #pragma unroll
        for (int q = 0; q < 4; ++q)
            #pragma unroll
            for (int s = 0; s < 4; ++s)
                ins4(KD[(q * 4 + s) * 64 + t], KI[(q * 4 + s) * 64 + t], bd, bi);
        #pragma unroll
        for (int s = 0; s < 4; ++s) NBR[t * 4 + s] = bi[s];
    }
    __syncthreads();

    // ---- nn1 accumulators (wave owns 24 jj channels, node = lane)
    float acc[24];
    const int jj0 = __builtin_amdgcn_readfirstlane(w * 24);
    #pragma unroll
    for (int i = 0; i < 24; ++i) acc[i] = (jj0 + i < 94) ? nn1b[jj0 + i] : 0.0f;

    // ---- HALF-MAJOR GEMM1 + nn1: for each 64-channel half of MLP2's output
    #pragma unroll 1
    for (int hf = 0; hf < 2; ++hf) {
        float mxq[2][2][4], smq[2][2][4];     // this half's agg [chunk][m][q]
        #pragma unroll 1
        for (int c = 0; c < 2; ++c) {
            if ((t >> 7) == c) {              // wave-uniform stage (waves 2c,2c+1)
                // MLP1 (recomputed per half -- bitwise-identical h1v)
                const int nl = t >> 2;
                const int kk = t & 3;
                const int n_g = node0 + nl;
                const int j   = NBR[nl * 4 + kk];
                float f[10];
                #pragma unroll
                for (int d = 0; d < 5; ++d) { f[d] = XS[n_g * 5 + d]; f[5 + d] = XS[j * 5 + d] - f[d]; }
                float h1v[64];
                #pragma unroll
                for (int cc = 0; cc < 64; ++cc) h1v[cc] = b1[cc];
                #pragma unroll
                for (int d = 0; d < 10; ++d) {
                    float fd = f[d];
                    #pragma unroll
                    for (int cc = 0; cc < 64; ++cc) h1v[cc] = fmaf(fd, W1[d * 64 + cc], h1v[cc]);
                }
                #pragma unroll
                for (int cc = 0; cc < 64; ++cc) h1v[cc] = fmaxf(h1v[cc], 0.0f);

                // pack to bf16 hi/lo planes, row = t&127
                const int rl = t & 127;
                unsigned int* dh = (unsigned int*)PH16 + rl * 36;
                unsigned int* dl = (unsigned int*)PL16 + rl * 36;
                #pragma unroll
                for (int i = 0; i < 8; ++i) {
                    unsigned int hw[4], lw[4];
                    #pragma unroll
                    for (int p = 0; p < 4; ++p) {
                        float va = h1v[i * 8 + p * 2], vb = h1v[i * 8 + p * 2 + 1];
                        unsigned short ha = f2bf(va), hb = f2bf(vb);
                        unsigned short la = f2bf(va - bf2f(ha)), lb = f2bf(vb - bf2f(hb));
                        hw[p] = (unsigned)ha | ((unsigned)hb << 16);
                        lw[p] = (unsigned)la | ((unsigned)lb << 16);
                    }
                    *(uint4*)(dh + 4 * i) = make_uint4(hw[0], hw[1], hw[2], hw[3]);
                    *(uint4*)(dl + 4 * i) = make_uint4(lw[0], lw[1], lw[2], lw[3]);
                }
            }
            __syncthreads();   // planes staged for chunk c

            f4v C[2][4];
            #pragma unroll
            for (int q = 0; q < 4; ++q) {
                float bv = b2[hf * 64 + q * 16 + (lane & 15)];
                #pragma unroll
                for (int m = 0; m < 2; ++m) {
                    C[m][q][0] = bv; C[m][q][1] = bv; C[m][q][2] = bv; C[m][q][3] = bv;
                }
            }
            #pragma unroll
            for (int ks = 0; ks < 2; ++ks) {
                s8v ah[2], al[2];
                #pragma unroll
                for (int m = 0; m < 2; ++m) {
                    const int row = (w << 5) + (m << 4) + (lane & 15);
                    const int ui  = row * 72 + (ks << 5) + ((lane >> 4) << 3);
                    ah[m] = *(const s8v*)(PH16 + ui);
                    al[m] = *(const s8v*)(PL16 + ui);
                }
                #pragma unroll
                for (int q = 0; q < 4; ++q) {
                    const int nt = hf * 4 + q;
                    const int bidx = ((((ks << 3) | nt) << 6) | lane) << 3;
                    s8v bh = *(const s8v*)(WBhi + bidx);
                    s8v bl = *(const s8v*)(WBlo + bidx);
                    #pragma unroll
                    for (int m = 0; m < 2; ++m) {
                        f4v cc = C[m][q];
                        cc = __builtin_amdgcn_mfma_f32_16x16x32_bf16(al[m], bh, cc, 0, 0, 0);
                        cc = __builtin_amdgcn_mfma_f32_16x16x32_bf16(ah[m], bl, cc, 0, 0, 0);
                        cc = __builtin_amdgcn_mfma_f32_16x16x32_bf16(ah[m], bh, cc, 0, 0, 0);
                        C[m][q] = cc;
                    }
                }
            }
            // relu + reduce over the lane's 4 rows (= one node's 4 edges)
            #pragma unroll
            for (int m = 0; m < 2; ++m)
                #pragma unroll
                for (int q = 0; q < 4; ++q) {
                    float a0 = fmaxf(C[m][q][0], 0.0f), a1 = fmaxf(C[m][q][1], 0.0f);
                    float a2 = fmaxf(C[m][q][2], 0.0f), a3 = fmaxf(C[m][q][3], 0.0f);
                    mxq[c][m][q] = fmaxf(fmaxf(a0, a1), fmaxf(a2, a3));
                    smq[c][m][q] = (a0 + a1) + (a2 + a3);
                }
            __syncthreads();   // planes consumed; next stage / AGM alias safe
        }

        // scatter this half's agg into AGM/AGS (R1-verified swizzled layout)
        #pragma unroll
        for (int c2 = 0; c2 < 2; ++c2)
            #pragma unroll
            for (int m = 0; m < 2; ++m)
                #pragma unroll
                for (int q = 0; q < 4; ++q) {
                    const int node = (c2 << 5) + (w << 3) + (m << 2) + (lane >> 4);
                    const int chl  = (q << 4) + (lane & 15);
                    const int ad   = (node << 6) + ((((chl >> 2) ^ node) & 15) << 2) + (chl & 3);
                    AGM[ad] = mxq[c2][m][q];
                    AGS[ad] = smq[c2][m][q];
                }
        __syncthreads();

        // nn1 partial for half hf: lane = node; agg rows via b128, chunks of 8
        for (int cb = 0; cb < 64; cb += 8) {
            float am[8], as_[8];
            #pragma unroll
            for (int i = 0; i < 2; ++i) {
                const int sw = ((((cb >> 2) + i) ^ lane) & 15) << 2;
                *(float4*)&am[i * 4]  = *(const float4*)&AGM[(lane << 6) + sw];
                *(float4*)&as_[i * 4] = *(const float4*)&AGS[(lane << 6) + sw];
            }
            #pragma unroll
            for (int i2 = 0; i2 < 24; ++i2) {
                const float* wa = WfT + (size_t)(jj0 + i2) * 256 + hf * 64 + cb;
                const float* wb = wa + 128;
                float a = acc[i2];
                #pragma unroll
                for (int i = 0; i < 8; ++i) a = fmaf(am[i], wa[i], fmaf(as_[i], wb[i], a));
                acc[i2] = a;
            }
        }
        __syncthreads();   // AGM/AGS dead; next half may restage planes
    }

    // ---- nnh = relu(nn1), channel-major [jj][node] (conflict-free stride 64)
    #pragma unroll
    for (int i2 = 0; i2 < 24; ++i2)
        if (jj0 + i2 < 94) NNH[(jj0 + i2) * 64 + lane] = fmaxf(acc[i2], 0.0f);
    __syncthreads();

    // ---- nn2: lane = node, wave owns 16 output channels (weights s_load).
    {
        const int ch0 = __builtin_amdgcn_readfirstlane(w * 16);
        float acc2[16];
        #pragma unroll
        for (int i = 0; i < 16; ++i) acc2[i] = nn2b[ch0 + i];
        #pragma unroll 1
        for (int cb = 0; cb < 64; cb += 32) {
            float hv[32];
            #pragma unroll
            for (int i = 0; i < 32; ++i) hv[i] = NNH[(cb + i) * 64 + lane];
            #pragma unroll
            for (int i = 0; i < 16; ++i) {
                const float* wp = nn2WT + (size_t)(ch0 + i) * 94 + cb;
                float a = acc2[i];
                #pragma unroll
                for (int c = 0; c < 32; ++c) a = fmaf(hv[c], wp[c], a);
                acc2[i] = a;
            }
        }
        {   // tail c = 64..93 (constant trip 30)
            float hv[30];
            #pragma unroll
            for (int i = 0; i < 30; ++i) hv[i] = NNH[(64 + i) * 64 + lane];
            #pragma unroll
            for (int i = 0; i < 16; ++i) {
                const float* wp = nn2WT + (size_t)(ch0 + i) * 94 + 64;
                float a = acc2[i];
                #pragma unroll
                for (int c = 0; c < 30; ++c) a = fmaf(hv[c], wp[c], a);
                acc2[i] = a;
            }
        }
        __syncthreads();   // NNH fully consumed; HT may alias
        #pragma unroll
        for (int i = 0; i < 8; ++i)
            *(float2*)&HT[lane * 66 + ch0 + i * 2] =
                make_float2(acc2[i * 2], acc2[i * 2 + 1]);
    }
    __syncthreads();

    // ---- partial pooling over this block's 64 nodes
    if (t < 64) {
        float mx = -3e38f, mn = 3e38f, sm = 0.0f;
        for (int n = 0; n < 64; ++n) {
            float v = HT[n * 66 + t];
            mx = fmaxf(mx, v); mn = fminf(mn, v); sm += v;
        }
        pmax[(size_t)blockIdx.x * 64 + t] = mx;
        pmin[(size_t)blockIdx.x * 64 + t] = mn;
        psum[(size_t)blockIdx.x * 64 + t] = sm;
    }
}

// ---------------------------------------------------------------------------
__global__ void k_pool(const float* __restrict__ pmax, const float* __restrict__ pmin,
                       const float* __restrict__ psum, float* __restrict__ g_out)
{
    const int t = threadIdx.x;
    const int g = blockIdx.x * 4 + (t >> 6);
    const int ch = t & 63;
    const size_t a = (size_t)(2 * g) * 64 + ch, b = a + 64;
    float mx = fmaxf(pmax[a], pmax[b]);
    float mn = fminf(pmin[a], pmin[b]);
    float sm = psum[a] + psum[b];
    float* gp = g_out + (size_t)g * 256;
    gp[ch]        = fmaxf(mx, 0.0f);
    gp[64 + ch]   = fmaxf(mn, 0.0f);
    gp[128 + ch]  = fmaxf(sm, 0.0f);
    gp[192 + ch]  = fmaxf(sm * (1.0f / 128.0f), 0.0f);
}

// ---------------------------------------------------------------------------
__global__ __launch_bounds__(128) void k_gru(
    const float* __restrict__ g, const float* __restrict__ h1_in,
    const float* __restrict__ wih0, const float* __restrict__ whh0,
    const float* __restrict__ bih0, const float* __restrict__ bhh0,
    const float* __restrict__ wih1, const float* __restrict__ whh1,
    const float* __restrict__ bih1, const float* __restrict__ bhh1,
    float* __restrict__ out1, float* __restrict__ hT)
{
    __shared__ float xt[4][256];
    __shared__ float h0[4][32];
    __shared__ float h1l[4][32];
    const int tid = threadIdx.x;
    const int e = tid >> 5;
    const int j = tid & 31;
    const int b = blockIdx.x * 4 + e;

    h0[e][j]  = h1_in[b * 32 + j];
    h1l[e][j] = h1_in[32768 + b * 32 + j];
    __syncthreads();

    for (int t = 0; t < 2; ++t) {
        for (int c = j; c < 256; c += 32)
            xt[e][c] = g[(size_t)(t * 1024 + 4 * c + (b >> 8)) * 256 + (b & 255)];
        __syncthreads();

        float gi0 = bih0[j], gi1 = bih0[32 + j], gi2 = bih0[64 + j];
        for (int c = 0; c < 256; ++c) {
            float xv = xt[e][c];
            gi0 += xv * wih0[j * 256 + c];
            gi1 += xv * wih0[(32 + j) * 256 + c];
            gi2 += xv * wih0[(64 + j) * 256 + c];
        }
        float gh0 = bhh0[j], gh1 = bhh0[32 + j], gh2 = bhh0[64 + j];
        #pragma unroll
        for (int c = 0; c < 32; ++c) {
            float hv = h0[e][c];
            gh0 += hv * whh0[j * 32 + c];
            gh1 += hv * whh0[(32 + j) * 32 + c];
            gh2 += hv * whh0[(64 + j) * 32 + c];
        }
        float r = 1.0f / (1.0f + expf(-(gi0 + gh0)));
        float z = 1.0f / (1.0f + expf(-(gi1 + gh1)));
        float nn = tanhf(gi2 + r * gh2);
        float hn0 = (1.0f - z) * nn + z * h0[e][j];
        __syncthreads();
        h0[e][j] = hn0;
        __syncthreads();

        float ai0 = bih1[j], ai1 = bih1[32 + j], ai2 = bih1[64 + j];
        #pragma unroll
        for (int c = 0; c < 32; ++c) {
            float xv = h0[e][c];
            ai0 += xv * wih1[j * 32 + c];
            ai1 += xv * wih1[(32 + j) * 32 + c];
            ai2 += xv * wih1[(64 + j) * 32 + c];
        }
        float ah0 = bhh1[j], ah1 = bhh1[32 + j], ah2 = bhh1[64 + j];
        #pragma unroll
        for (int c = 0; c < 32; ++c) {
            float hv = h1l[e][c];
            ah0 += hv * whh1[j * 32 + c];
            ah1 += hv * whh1[(32 + j) * 32 + c];
            ah2 += hv * whh1[(64 + j) * 32 + c];
        }
        float r1 = 1.0f / (1.0f + expf(-(ai0 + ah0)));
        float z1 = 1.0f / (1.0f + expf(-(ai1 + ah1)));
        float n1 = tanhf(ai2 + r1 * ah2);
        float hn1 = (1.0f - z1) * n1 + z1 * h1l[e][j];
        __syncthreads();
        h1l[e][j] = hn1;
        out1[(size_t)(t * 1024 + b) * 32 + j] = hn1;
        __syncthreads();
    }
    hT[b * 32 + j]         = h0[e][j];
    hT[32768 + b * 32 + j] = h1l[e][j];
}

__global__ void k_final(const float* __restrict__ out1,
                        const float* __restrict__ nn4W, const float* __restrict__ nn4b,
                        float* __restrict__ y)
{
    const int r = blockIdx.x * 256 + threadIdx.x;
    if (r >= 2048) return;
    const int t = r >> 10, rp = r & 1023;
    const int f = rp >> 5, bb0 = (rp & 31) << 5;
    float acc = nn4b[0];
    #pragma unroll
    for (int c = 0; c < 32; ++c)
        acc += fmaxf(out1[(size_t)(t * 1024 + bb0 + c) * 32 + f], 0.0f) * nn4W[c];
    y[r] = fmaxf(acc, 0.0f);
}

extern "C" void kernel_launch(void* const* d_in, const int* in_sizes, int n_in,
                              void* d_out, int out_size, void* d_ws, size_t ws_size,
                              hipStream_t stream) {
    const float* x    = (const float*)d_in[0];
    const float* h1i  = (const float*)d_in[2];
    const float* W1   = (const float*)d_in[3];
    const float* b1   = (const float*)d_in[4];
    const float* W2   = (const float*)d_in[5];
    const float* b2   = (const float*)d_in[6];
    const float* nn1W = (const float*)d_in[7];
    const float* nn1b = (const float*)d_in[8];
    const float* nn2W = (const float*)d_in[9];
    const float* nn2b = (const float*)d_in[10];
    const float* nn4W = (const float*)d_in[11];
    const float* nn4b = (const float*)d_in[12];
    const float* wih0 = (const float*)d_in[13];
    const float* whh0 = (const float*)d_in[14];
    const float* bih0 = (const float*)d_in[15];
    const float* bhh0 = (const float*)d_in[16];
    const float* wih1 = (const float*)d_in[17];
    const float* whh1 = (const float*)d_in[18];
    const float* bih1 = (const float*)d_in[19];
    const float* bhh1 = (const float*)d_in[20];

    float* ws = (float*)d_ws;
    float* g_buf  = ws;                   // 524288
    float* out1   = g_buf + 524288;       // 65536
    float* nn2WT  = out1 + 65536;         // 6016
    float* WfT    = nn2WT + 6016;         // 24576 (96x256)
    float* pmax   = WfT + 24576;          // 262144
    float* pmin   = pmax + 262144;        // 262144
    float* psum   = pmin + 262144;        // 262144
    unsigned short* WBhi = (unsigned short*)(psum + 262144);  // 8192 u16
    unsigned short* WBlo = WBhi + 8192;                       // 8192 u16

    float* y  = (float*)d_out;            // [2048]
    float* hT = y + 2048;                 // [2,1024,32]

    hipLaunchKernelGGL(k_prep, dim3(152), dim3(256), 0, stream,
                       W2, nn2W, nn1W, nn2WT, WfT, WBhi, WBlo);
    hipLaunchKernelGGL(k_edge, dim3(4096), dim3(256), 0, stream,
                       x, W1, b1, b2, WBhi, WBlo, WfT, nn1b, nn2WT, nn2b,
                       pmax, pmin, psum);
    hipLaunchKernelGGL(k_pool, dim3(512), dim3(256), 0, stream,
                       pmax, pmin, psum, g_buf);
    hipLaunchKernelGGL(k_gru, dim3(256), dim3(128), 0, stream,
                       g_buf, h1i, wih0, whh0, bih0, bhh0,
                       wih1, whh1, bih1, bhh1, out1, hT);
    hipLaunchKernelGGL(k_final, dim3(8), dim3(256), 0, stream,
                       out1, nn4W, nn4b, y);
}